// Round 10
// baseline (203.352 us; speedup 1.0000x reference)
//
#include <hip/hip_runtime.h>
#include <math.h>

#define HH 2048
#define WW 2048
#define PLANE 4194304        // HH*WW
#define PITCH 45             // odd pitch; all stages <=2-way banks (free)
#define TR 25                // halo rows (15-row output tile)
#define PP (TR*PITCH)        // 1125 floats per plane
#define NBLK 8768            // 64 x-tiles * 137 y-tiles
#define CHUNK 1096           // NBLK/8

// ws layout (bytes):
// 0     : float gwin[11]
// 64    : float gwin3[11]
// 128   : double lG[4]
// 256   : double lYpart[4*528]   (16896 B)
// 17408 : double qpart[8768]     (70144 B)

__device__ inline double wave_red(double v) {
#pragma unroll
  for (int o = 32; o > 0; o >>= 1) v += __shfl_down(v, o, 64);
  return v;
}

__global__ void k0_window(float* gwin, float* gwin3) {
  if (threadIdx.x == 0) {
    double e[11], s = 0.0;
    double sig = 11.0 / 6.0;
    for (int i = 0; i < 11; ++i) {
      double x = (double)(i - 5);
      e[i] = exp(-(x * x) / (2.0 * sig * sig));
      s += e[i];
    }
    for (int i = 0; i < 11; ++i) {
      gwin[i]  = (float)(e[i] / s);
      gwin3[i] = (float)(e[i] / (3.0 * s));
    }
  }
}

// k1: lY partial sums (unchanged; ~18 us).
__global__ __launch_bounds__(256) void k1_lY(const float* __restrict__ Ys,
                                             const float* __restrict__ gwin,
                                             double* __restrict__ lYpart) {
  int bid = blockIdx.x;
  int tid = threadIdx.x;
  double acc = 0.0;
  __shared__ float P[12];
  __shared__ double red[4];

  if (bid < 2048) {
    const float4* __restrict__ p = (const float4*)Ys;
    int base = bid * 6144 + tid;
#pragma unroll 1
    for (int gblk = 0; gblk < 3; ++gblk) {
      float ax = 0.f, ay = 0.f;
#pragma unroll
      for (int u = 0; u < 8; ++u) {
        float4 v = p[base + (gblk * 8 + u) * 256];
        ax += v.x + v.z;
        ay += v.y + v.w;
      }
      acc += (double)(ax + ay);
    }
  } else {
    int b = bid - 2048;             // 0..63
    int k = b >> 4, sub = b & 15;
    if (tid == 0) {
      float s = 0.f;
      for (int i = 0; i < 12; ++i) { P[i] = s; if (i < 11) s += gwin[i]; }
    }
    __syncthreads();
    const float4* __restrict__ Yk4 = (const float4*)(Ys + (size_t)k * 3 * PLANE);
    auto covP = [&](int r) -> float {
      if (r >= 5 && r <= 2042) return 1.0f;
      int dhi = r + 5; if (dhi > 10) dhi = 10;
      int dlo = r - 2042; if (dlo < 0) dlo = 0;
      return P[dhi + 1] - P[dlo];
    };
#pragma unroll 1
    for (int t = sub * 256 + tid; t < 39816; t += 4096) {
      int ch, row, g4;
      if (t < 15360) {
        ch = t / 5120;
        int r = (t % 5120) / 512;
        g4 = t & 511;
        row = (r < 5) ? r : r + 2038;
      } else {
        int u = t - 15360;
        ch = u / 8152;
        int rem = u % 8152;
        row = 5 + (rem >> 2);
        int gi = rem & 3;
        g4 = (gi < 2) ? gi : 508 + gi;
      }
      float4 v = Yk4[ch * 1048576 + row * 512 + g4];
      float cy = covP(row);
      int x0 = g4 << 2;
      float w0 = cy * covP(x0)     - 1.0f;
      float w1 = cy * covP(x0 + 1) - 1.0f;
      float w2 = cy * covP(x0 + 2) - 1.0f;
      float w3 = cy * covP(x0 + 3) - 1.0f;
      acc += (double)(w0 * v.x + w1 * v.y + w2 * v.z + w3 * v.w);
    }
  }

  acc = wave_red(acc);
  int lane = tid & 63, wid = tid >> 6;
  __syncthreads();
  if (lane == 0) red[wid] = acc;
  __syncthreads();
  if (tid == 0) {
    double tot = red[0] + red[1] + red[2] + red[3];
    if (bid < 2048) {
      int k = bid >> 9;
      lYpart[k * 528 + (bid & 511)] = tot;
    } else {
      int b = bid - 2048;
      lYpart[(b >> 4) * 528 + 512 + (b & 15)] = tot;
    }
  }
}

__global__ __launch_bounds__(256) void k2a_lG(const double* __restrict__ lYpart,
                                              double* __restrict__ lG) {
  __shared__ double red[4];
  for (int k = 0; k < 4; ++k) {
    const double* p = lYpart + k * 528;
    double v = p[threadIdx.x] + p[256 + threadIdx.x];
    if (threadIdx.x < 16) v += p[512 + threadIdx.x];
    v = wave_red(v);
    int lane = threadIdx.x & 63, wid = threadIdx.x >> 6;
    if (lane == 0) red[wid] = v;
    __syncthreads();
    if (threadIdx.x == 0) {
      double tot = red[0] + red[1] + red[2] + red[3];
      double lY = tot * (1.0 / 12582912.0);
      double d = lY - 0.5;
      lG[k] = exp(-(d * d) / 0.08);
    }
    __syncthreads();
  }
}

// k2 v10: 32x15 output tile, halo cols [x0-6, x0+37] (44 wide, even start),
// halo rows [y0-5, y0+19] (25). Pitch 45, b32 stages, float2 global loads
// spread over ALL 512 threads. B = r8's group-of-8 snapshot form.
__global__ __launch_bounds__(512, 2) void k2_main(const float* __restrict__ X,
                                                  const float* __restrict__ Ys,
                                                  const float* __restrict__ gwin,
                                                  const float* __restrict__ gwin3,
                                                  const double* __restrict__ lG,
                                                  double* __restrict__ qpart) {
  __shared__ float prod[14 * PP];   // 63,000 B
  __shared__ double qred[8];

  int bid = blockIdx.x;
  int wg = (bid & 7) * CHUNK + (bid >> 3);   // XCD-compact swizzle (bijective)
  int tX = wg & 63, tY = wg >> 6;            // 64 x-tiles, 137 y-tiles
  int x0 = tX * 32, y0 = tY * 15;
  int tid = threadIdx.x;

  float g[11], g3[11];
#pragma unroll
  for (int i = 0; i < 11; ++i) { g[i] = gwin[i]; g3[i] = gwin3[i]; }

  // ---- Stage A: 25 rows x 22 float2-cols = 550 tasks over all threads ----
  const size_t PL = (size_t)HH * WW;
#pragma unroll 1
  for (int pos = tid; pos < 550; pos += 512) {
    int row = pos / 22;
    int c2 = pos - row * 22;
    int gy = y0 - 5 + row;
    int gx = x0 - 6 + 2 * c2;           // even
    bool ok = ((unsigned)gy < (unsigned)HH) && ((unsigned)gx < (unsigned)(WW - 1));
    size_t off = ok ? ((size_t)gy * WW + gx) : 0;
    float xa0 = 0.f, xa1 = 0.f, xb0 = 0.f, xb1 = 0.f, xc0 = 0.f, xc1 = 0.f;
    if (ok) {
      float2 t0 = *(const float2*)(X + off);
      float2 t1 = *(const float2*)(X + off + PL);
      float2 t2 = *(const float2*)(X + off + 2 * PL);
      xa0 = t0.x; xa1 = t0.y; xb0 = t1.x; xb1 = t1.y; xc0 = t2.x; xc1 = t2.y;
    }
    int o = row * PITCH + 2 * c2;
    prod[0 * PP + o]     = xa0 + xb0 + xc0;
    prod[0 * PP + o + 1] = xa1 + xb1 + xc1;
    prod[1 * PP + o]     = xa0 * xa0 + xb0 * xb0 + xc0 * xc0;
    prod[1 * PP + o + 1] = xa1 * xa1 + xb1 * xb1 + xc1 * xc1;
#pragma unroll
    for (int k = 0; k < 4; ++k) {
      float ya0 = 0.f, ya1 = 0.f, yb0 = 0.f, yb1 = 0.f, yc0 = 0.f, yc1 = 0.f;
      if (ok) {
        const float* Yk = Ys + (size_t)(3 * k) * PLANE;
        float2 t0 = *(const float2*)(Yk + off);
        float2 t1 = *(const float2*)(Yk + off + PL);
        float2 t2 = *(const float2*)(Yk + off + 2 * PL);
        ya0 = t0.x; ya1 = t0.y; yb0 = t1.x; yb1 = t1.y; yc0 = t2.x; yc1 = t2.y;
      }
      prod[(2 + k) * PP + o]      = ya0 + yb0 + yc0;
      prod[(2 + k) * PP + o + 1]  = ya1 + yb1 + yc1;
      prod[(6 + k) * PP + o]      = ya0 * ya0 + yb0 * yb0 + yc0 * yc0;
      prod[(6 + k) * PP + o + 1]  = ya1 * ya1 + yb1 * yb1 + yc1 * yc1;
      prod[(10 + k) * PP + o]     = xa0 * ya0 + xb0 * yb0 + xc0 * yc0;
      prod[(10 + k) * PP + o + 1] = xa1 * ya1 + xb1 * yb1 + xc1 * yc1;
    }
  }
  __syncthreads();

  // ---- Stage B: H-blur, group-of-8, snapshot/barrier (r8-proven form) ----
  // 14 fields x 25 rows x 4 groups = 1400 tasks. Output col c written at halo
  // col c; window = halo cols c+1 .. c+11.
#pragma unroll 1
  for (int it = 0; it < 3; ++it) {
    int t = it * 512 + tid;
    bool valid = t < 1400;
    int f = 0, row = 0, xg = 0;
    float w[18];
    if (valid) {
      f = t / 100;
      int rr = t - f * 100;
      row = rr >> 2;
      xg = (rr & 3) * 8;
      int base = f * PP + row * PITCH + xg;
#pragma unroll
      for (int j = 0; j < 18; ++j) w[j] = prod[base + 1 + j];
    }
    __syncthreads();
    if (valid) {
      int base = f * PP + row * PITCH + xg;
#pragma unroll
      for (int o = 0; o < 8; ++o) {
        float s = 0.f;
#pragma unroll
        for (int d = 0; d < 11; ++d) s += g[d] * w[o + d];
        prod[base + o] = s;
      }
    }
    __syncthreads();
  }

  // ---- Stage C: V-blur, column-owned (taps include /3) ----
  if (tid < 448) {                 // 14 fields x 32 columns
    int f = tid >> 5, tx = tid & 31;
    float* bp = prod + f * PP + tx;
    float col[25];
#pragma unroll
    for (int j = 0; j < TR; ++j) col[j] = bp[j * PITCH];
#pragma unroll
    for (int ty = 0; ty < 15; ++ty) {
      float s = 0.f;
#pragma unroll
      for (int d = 0; d < 11; ++d) s += g3[d] * col[ty + d];
      bp[ty * PITCH] = s;
    }
  }
  __syncthreads();

  // ---- Stage D: per-pixel fusion + block reduction ----
  {
    int dty = tid >> 5, dtx = tid & 31;
    double v = 0.0;
    if (dty < 15 && (y0 + dty) < HH) {
      int o = dty * PITCH + dtx;
      float b[14];
#pragma unroll
      for (int f = 0; f < 14; ++f) b[f] = prod[f * PP + o];
      float muX = b[0];
      float muX2 = muX * muX;
      float sigX = b[1] - muX2;
      float num = 0.f, den = 0.f;
      float best_sig = -1e30f, best_cs = 0.f;
#pragma unroll
      for (int k = 0; k < 4; ++k) {
        float muY  = b[2 + k];
        float sigY = b[6 + k] - muY * muY;
        float sXY  = b[10 + k] - muX * muY;
        float cs = (2.f * sXY + 9e-4f) / (sigX + sigY + 9e-4f);
        if (sigY > best_sig) { best_sig = sigY; best_cs = cs; }
        float dm = muY - 0.5f;
        float lL = expf(-dm * dm * 12.5f);
        float LY = (float)lG[k] * lL;
        num += LY * muY;
        den += LY;
      }
      float muYw = num / den;
      float l = (2.f * muX * muYw + 1e-4f) / (muX2 + muYw * muYw + 1e-4f);
      v = (double)(l * best_cs);
    }
    v = wave_red(v);
    int lane = tid & 63, wid = tid >> 6;
    if (lane == 0) qred[wid] = v;
    __syncthreads();
    if (tid == 0) {
      double t = 0.0;
#pragma unroll
      for (int i = 0; i < 8; ++i) t += qred[i];
      qpart[bid] = t;
    }
  }
}

__global__ __launch_bounds__(512) void k3_final(const double* __restrict__ qpart,
                                                float* __restrict__ out) {
  double acc = 0.0;
  for (int i = threadIdx.x; i < NBLK; i += 512) acc += qpart[i];
  acc = wave_red(acc);
  __shared__ double red[8];
  int lane = threadIdx.x & 63, wid = threadIdx.x >> 6;
  if (lane == 0) red[wid] = acc;
  __syncthreads();
  if (threadIdx.x == 0)
    out[0] = (float)((red[0] + red[1] + red[2] + red[3] +
                      red[4] + red[5] + red[6] + red[7]) * (1.0 / 4194304.0));
}

extern "C" void kernel_launch(void* const* d_in, const int* in_sizes, int n_in,
                              void* d_out, int out_size, void* d_ws, size_t ws_size,
                              hipStream_t stream) {
  const float* X  = (const float*)d_in[0];
  const float* Ys = (const float*)d_in[1];
  char* ws = (char*)d_ws;
  float*  gwin   = (float*)(ws + 0);
  float*  gwin3  = (float*)(ws + 64);
  double* lG     = (double*)(ws + 128);
  double* lYpart = (double*)(ws + 256);
  double* qpart  = (double*)(ws + 17408);
  float* out = (float*)d_out;

  hipLaunchKernelGGL(k0_window, dim3(1), dim3(64), 0, stream, gwin, gwin3);
  hipLaunchKernelGGL(k1_lY, dim3(2112), dim3(256), 0, stream, Ys, gwin, lYpart);
  hipLaunchKernelGGL(k2a_lG, dim3(1), dim3(256), 0, stream, lYpart, lG);
  hipLaunchKernelGGL(k2_main, dim3(NBLK), dim3(512), 0, stream, X, Ys, gwin, gwin3, lG, qpart);
  hipLaunchKernelGGL(k3_final, dim3(1), dim3(512), 0, stream, qpart, out);
}

// Round 11
// 163.809 us; speedup vs baseline: 1.2414x; 1.2414x over previous
//
#include <hip/hip_runtime.h>
#include <math.h>

#define HH 2048
#define WW 2048
#define PLANE 4194304        // HH*WW
#define PITCH 43             // odd pitch: conflict-free b32 LDS (r1/r2/r8-proven)
#define PP (26*PITCH)        // per-field plane size (floats)

// ws layout (bytes):
// 0     : float gwin[11]
// 64    : float gwin3[11]
// 128   : double lG[4]
// 256   : double lYpart[4*528]   (16896 B)
// 17408 : double qpart[8192]     (65536 B)

__device__ inline double wave_red(double v) {
#pragma unroll
  for (int o = 32; o > 0; o >>= 1) v += __shfl_down(v, o, 64);
  return v;
}

__global__ void k0_window(float* gwin, float* gwin3) {
  if (threadIdx.x == 0) {
    double e[11], s = 0.0;
    double sig = 11.0 / 6.0;
    for (int i = 0; i < 11; ++i) {
      double x = (double)(i - 5);
      e[i] = exp(-(x * x) / (2.0 * sig * sig));
      s += e[i];
    }
    for (int i = 0; i < 11; ++i) {
      gwin[i]  = (float)(e[i] / s);
      gwin3[i] = (float)(e[i] / (3.0 * s));
    }
  }
}

// k1: lY partial sums (~18 us, L3-bandwidth-bound).
__global__ __launch_bounds__(256) void k1_lY(const float* __restrict__ Ys,
                                             const float* __restrict__ gwin,
                                             double* __restrict__ lYpart) {
  int bid = blockIdx.x;
  int tid = threadIdx.x;
  double acc = 0.0;
  __shared__ float P[12];
  __shared__ double red[4];

  if (bid < 2048) {
    const float4* __restrict__ p = (const float4*)Ys;
    int base = bid * 6144 + tid;
#pragma unroll 1
    for (int gblk = 0; gblk < 3; ++gblk) {
      float ax = 0.f, ay = 0.f;
#pragma unroll
      for (int u = 0; u < 8; ++u) {
        float4 v = p[base + (gblk * 8 + u) * 256];
        ax += v.x + v.z;
        ay += v.y + v.w;
      }
      acc += (double)(ax + ay);
    }
  } else {
    int b = bid - 2048;             // 0..63
    int k = b >> 4, sub = b & 15;
    if (tid == 0) {
      float s = 0.f;
      for (int i = 0; i < 12; ++i) { P[i] = s; if (i < 11) s += gwin[i]; }
    }
    __syncthreads();
    const float4* __restrict__ Yk4 = (const float4*)(Ys + (size_t)k * 3 * PLANE);
    auto covP = [&](int r) -> float {
      if (r >= 5 && r <= 2042) return 1.0f;
      int dhi = r + 5; if (dhi > 10) dhi = 10;
      int dlo = r - 2042; if (dlo < 0) dlo = 0;
      return P[dhi + 1] - P[dlo];
    };
#pragma unroll 1
    for (int t = sub * 256 + tid; t < 39816; t += 4096) {
      int ch, row, g4;
      if (t < 15360) {
        ch = t / 5120;
        int r = (t % 5120) / 512;
        g4 = t & 511;
        row = (r < 5) ? r : r + 2038;
      } else {
        int u = t - 15360;
        ch = u / 8152;
        int rem = u % 8152;
        row = 5 + (rem >> 2);
        int gi = rem & 3;
        g4 = (gi < 2) ? gi : 508 + gi;
      }
      float4 v = Yk4[ch * 1048576 + row * 512 + g4];
      float cy = covP(row);
      int x0 = g4 << 2;
      float w0 = cy * covP(x0)     - 1.0f;
      float w1 = cy * covP(x0 + 1) - 1.0f;
      float w2 = cy * covP(x0 + 2) - 1.0f;
      float w3 = cy * covP(x0 + 3) - 1.0f;
      acc += (double)(w0 * v.x + w1 * v.y + w2 * v.z + w3 * v.w);
    }
  }

  acc = wave_red(acc);
  int lane = tid & 63, wid = tid >> 6;
  __syncthreads();
  if (lane == 0) red[wid] = acc;
  __syncthreads();
  if (tid == 0) {
    double tot = red[0] + red[1] + red[2] + red[3];
    if (bid < 2048) {
      int k = bid >> 9;
      lYpart[k * 528 + (bid & 511)] = tot;
    } else {
      int b = bid - 2048;
      lYpart[(b >> 4) * 528 + 512 + (b & 15)] = tot;
    }
  }
}

__global__ __launch_bounds__(256) void k2a_lG(const double* __restrict__ lYpart,
                                              double* __restrict__ lG) {
  __shared__ double red[4];
  for (int k = 0; k < 4; ++k) {
    const double* p = lYpart + k * 528;
    double v = p[threadIdx.x] + p[256 + threadIdx.x];
    if (threadIdx.x < 16) v += p[512 + threadIdx.x];
    v = wave_red(v);
    int lane = threadIdx.x & 63, wid = threadIdx.x >> 6;
    if (lane == 0) red[wid] = v;
    __syncthreads();
    if (threadIdx.x == 0) {
      double tot = red[0] + red[1] + red[2] + red[3];
      double lY = tot * (1.0 / 12582912.0);
      double d = lY - 0.5;
      lG[k] = exp(-(d * d) / 0.08);
    }
    __syncthreads();
  }
}

// k2: measured-best (r8). 32x16 output tile, 42x26 halo, 14 product fields,
// in-place separable blur in LDS (pitch 43, b32, conflict-free), per-pixel
// fusion, block partial of l*cs. VALU ~73% / LDS-pipe ~70% co-saturated.
__global__ __launch_bounds__(512) void k2_main(const float* __restrict__ X,
                                               const float* __restrict__ Ys,
                                               const float* __restrict__ gwin,
                                               const float* __restrict__ gwin3,
                                               const double* __restrict__ lG,
                                               double* __restrict__ qpart) {
  __shared__ float prod[14 * PP];   // 62,608 B
  __shared__ double qred[8];

  int bid = blockIdx.x;
  // XCD-compact swizzle (8192 % 8 == 0, bijective): x-adjacent tiles share L2
  int wg = (bid & 7) * 1024 + (bid >> 3);
  int tX = wg & 63, tY = wg >> 6;     // 64 x-tiles, 128 y-tiles
  int x0 = tX * 32, y0 = tY * 16;
  int tid = threadIdx.x;

  float g[11], g3[11];
#pragma unroll
  for (int i = 0; i < 11; ++i) { g[i] = gwin[i]; g3[i] = gwin3[i]; }

  // ---- Stage A: channel-collapsed products into LDS planes (halo 42x26) ----
  const size_t PL = (size_t)HH * WW;
  for (int pos = tid; pos < 42 * 26; pos += 512) {
    int py = pos / 42;
    int px = pos - py * 42;
    int gy = y0 - 5 + py;
    int gx = x0 - 5 + px;
    float xv0 = 0.f, xv1 = 0.f, xv2 = 0.f;
    float yv[12];
#pragma unroll
    for (int j = 0; j < 12; ++j) yv[j] = 0.f;
    if ((unsigned)gy < (unsigned)HH && (unsigned)gx < (unsigned)WW) {
      size_t off = (size_t)gy * WW + gx;
      xv0 = X[off];
      xv1 = X[off + PL];
      xv2 = X[off + 2 * PL];
#pragma unroll
      for (int j = 0; j < 12; ++j) yv[j] = Ys[off + (size_t)j * PL];
    }
    int o = py * PITCH + px;
    prod[0 * PP + o] = xv0 + xv1 + xv2;
    prod[1 * PP + o] = xv0 * xv0 + xv1 * xv1 + xv2 * xv2;
#pragma unroll
    for (int k = 0; k < 4; ++k) {
      float a = yv[3 * k], b = yv[3 * k + 1], c = yv[3 * k + 2];
      prod[(2 + k) * PP + o]  = a + b + c;
      prod[(6 + k) * PP + o]  = a * a + b * b + c * c;
      prod[(10 + k) * PP + o] = xv0 * a + xv1 * b + xv2 * c;
    }
  }
  __syncthreads();

  // ---- Stage B: horizontal 11-tap blur, in place, register sliding window ----
#pragma unroll 1
  for (int it = 0; it < 3; ++it) {
    int t = it * 512 + tid;
    bool valid = t < 1456;
    int f = 0, py = 0, xg = 0;
    float w[18];
    if (valid) {
      f = t / 104;
      int rr = t - f * 104;
      py = rr >> 2;
      xg = (rr & 3) * 8;
      int base = f * PP + py * PITCH + xg;
#pragma unroll
      for (int j = 0; j < 18; ++j) w[j] = prod[base + j];
    }
    __syncthreads();
    if (valid) {
      int base = f * PP + py * PITCH + xg;
#pragma unroll
      for (int o = 0; o < 8; ++o) {
        float s = 0.f;
#pragma unroll
        for (int d = 0; d < 11; ++d) s += g[d] * w[o + d];
        prod[base + o] = s;
      }
    }
    __syncthreads();
  }

  // ---- Stage C: vertical 11-tap blur (taps include /3), thread-per-column ----
  if (tid < 448) {                 // 14 fields x 32 columns
    int f = tid >> 5, tx = tid & 31;
    int base = f * PP + tx;
    float col[26];
#pragma unroll
    for (int py = 0; py < 26; ++py) col[py] = prod[base + py * PITCH];
#pragma unroll
    for (int ty = 0; ty < 16; ++ty) {
      float s = 0.f;
#pragma unroll
      for (int d = 0; d < 11; ++d) s += g3[d] * col[ty + d];
      prod[base + ty * PITCH] = s;
    }
  }
  __syncthreads();

  // ---- Stage D: per-pixel fusion + block reduction ----
  {
    int ty = tid >> 5, tx = tid & 31;   // 512 threads = full 16x32 tile
    int o = ty * PITCH + tx;
    float b[14];
#pragma unroll
    for (int f = 0; f < 14; ++f) b[f] = prod[f * PP + o];
    float muX = b[0];
    float muX2 = muX * muX;
    float sigX = b[1] - muX2;
    float num = 0.f, den = 0.f;
    float best_sig = -1e30f, best_cs = 0.f;
#pragma unroll
    for (int k = 0; k < 4; ++k) {
      float muY  = b[2 + k];
      float sigY = b[6 + k] - muY * muY;
      float sXY  = b[10 + k] - muX * muY;
      float cs = (2.f * sXY + 9e-4f) / (sigX + sigY + 9e-4f);
      if (sigY > best_sig) { best_sig = sigY; best_cs = cs; }  // first-max wins
      float dm = muY - 0.5f;
      float lL = expf(-dm * dm * 12.5f);          // /DENOM_L = *12.5
      float LY = (float)lG[k] * lL;
      num += LY * muY;
      den += LY;
    }
    float muYw = num / den;
    float l = (2.f * muX * muYw + 1e-4f) / (muX2 + muYw * muYw + 1e-4f);
    double v = (double)(l * best_cs);
    v = wave_red(v);
    int lane = tid & 63, wid = tid >> 6;
    if (lane == 0) qred[wid] = v;
    __syncthreads();
    if (tid == 0) {
      double t = 0.0;
#pragma unroll
      for (int i = 0; i < 8; ++i) t += qred[i];
      qpart[blockIdx.x] = t;
    }
  }
}

__global__ __launch_bounds__(512) void k3_final(const double* __restrict__ qpart,
                                                float* __restrict__ out) {
  double acc = 0.0;
  for (int i = threadIdx.x; i < 8192; i += 512) acc += qpart[i];
  acc = wave_red(acc);
  __shared__ double red[8];
  int lane = threadIdx.x & 63, wid = threadIdx.x >> 6;
  if (lane == 0) red[wid] = acc;
  __syncthreads();
  if (threadIdx.x == 0)
    out[0] = (float)((red[0] + red[1] + red[2] + red[3] +
                      red[4] + red[5] + red[6] + red[7]) * (1.0 / 4194304.0));
}

extern "C" void kernel_launch(void* const* d_in, const int* in_sizes, int n_in,
                              void* d_out, int out_size, void* d_ws, size_t ws_size,
                              hipStream_t stream) {
  const float* X  = (const float*)d_in[0];
  const float* Ys = (const float*)d_in[1];
  char* ws = (char*)d_ws;
  float*  gwin   = (float*)(ws + 0);
  float*  gwin3  = (float*)(ws + 64);
  double* lG     = (double*)(ws + 128);
  double* lYpart = (double*)(ws + 256);
  double* qpart  = (double*)(ws + 17408);
  float* out = (float*)d_out;

  hipLaunchKernelGGL(k0_window, dim3(1), dim3(64), 0, stream, gwin, gwin3);
  hipLaunchKernelGGL(k1_lY, dim3(2112), dim3(256), 0, stream, Ys, gwin, lYpart);
  hipLaunchKernelGGL(k2a_lG, dim3(1), dim3(256), 0, stream, lYpart, lG);
  hipLaunchKernelGGL(k2_main, dim3(8192), dim3(512), 0, stream, X, Ys, gwin, gwin3, lG, qpart);
  hipLaunchKernelGGL(k3_final, dim3(1), dim3(512), 0, stream, qpart, out);
}